// Round 11
// baseline (272.060 us; speedup 1.0000x reference)
//
#include <hip/hip_runtime.h>
#include <hip/hip_bf16.h>

#define T_DIM 1024
#define B_DIM 8
#define D_DIM 2048
#define E_DIM 6144   // 3*D
#define N_ROWS 8192  // T*B
#define K_DIM 2048
#define LN_EPS 1e-5f

#define S2  128   // scan chunks
#define CH2 8     // T per chunk
#define BD (B_DIM * D_DIM)  // 16384

typedef short bf16x8 __attribute__((ext_vector_type(8)));
typedef unsigned short u16x8 __attribute__((ext_vector_type(8)));
typedef float f32x4 __attribute__((ext_vector_type(4)));

__device__ __forceinline__ unsigned short f2bf(float f) {
  unsigned u = __float_as_uint(f);
  u += 0x7fffu + ((u >> 16) & 1u);  // round-to-nearest-even
  return (unsigned short)(u >> 16);
}
__device__ __forceinline__ float bf2f(unsigned short h) {
  return __uint_as_float(((unsigned)h) << 16);
}
__device__ __forceinline__ float fast_sigmoid(float x) {
  return __builtin_amdgcn_rcpf(1.f + __expf(-x));
}
__device__ __forceinline__ float fast_tanh(float x) {
  return 1.f - 2.f * __builtin_amdgcn_rcpf(__expf(2.f * x) + 1.f);
}

// ------- f32 -> bf16 conversion (8 elems/thread, 16B stores) -------
__global__ __launch_bounds__(256) void cvt2_kernel(
    const float* __restrict__ src0, unsigned short* __restrict__ dst0, int n0,
    const float* __restrict__ src1, unsigned short* __restrict__ dst1, int n1) {
  int i = blockIdx.x * 256 + threadIdx.x;  // group of 8 floats
  const float* s;
  unsigned short* d;
  if (i < n0) {
    s = src0; d = dst0;
  } else {
    i -= n0;
    if (i >= n1) return;
    s = src1; d = dst1;
  }
  float4 v0 = reinterpret_cast<const float4*>(s)[i * 2];
  float4 v1 = reinterpret_cast<const float4*>(s)[i * 2 + 1];
  u16x8 o;
  o[0] = f2bf(v0.x); o[1] = f2bf(v0.y); o[2] = f2bf(v0.z); o[3] = f2bf(v0.w);
  o[4] = f2bf(v1.x); o[5] = f2bf(v1.y); o[6] = f2bf(v1.z); o[7] = f2bf(v1.w);
  *reinterpret_cast<u16x8*>(d + (size_t)i * 8) = o;
}

// ============ 256x256 8-phase bf16 MFMA GEMM (T1+T2+T3/T4+T5) ============
// C[N_ROWS,E] = A[N_ROWS,K] * Bw[E,K]^T, all bf16, f32 accumulate.
// 512 threads = 8 waves (2M x 4N). BK=64. LDS = 2 buffers x (A 32KB + B 32KB).
// Half-tile layout: 2 k-panels (ks=0/1) of [128 rows][32 bf16] (64B rows),
// swizzled byte^=((b>>9)&1)<<5; staged linear-dest with inverse-swz source.
//
// R2: ds_reads software-pipelined ONE PHASE AHEAD. R9: no explicit phase-top
// lgkmcnt(0) (compiler emits fine-grained per-use waits).
// R11 (fixes R10's vmcnt miscount): deep prefetch with vmcnt(8).
// Ph3 queue = (j+1,h1..h3)=6 oldest, (j+2,h0)=2, (j+2,h1..h3)=6.
// vmcnt(8) drains EXACTLY tile j+1's remainder and leaves all 8 of tile
// (j+2)'s loads in flight with a full iteration (~2800cy) to land.
// (R10's vmcnt(6) also drained (j+2,h0) — a load issued one phase earlier —
// serializing every iteration; that was the 175->205us regression.)
// Hazard audit (q+2 rule): buf A-h1 last read-issue ph0 -> write ph3 =
// 3 barriers ✓; buf B h2/h3 last read-issue ph1 -> write ph3 = 2 ✓;
// buf A-h0 last read-issue ph0 -> write ph2 = 2 ✓; ph3 hoist reads nbuf ✓.
// NOTE (R4 lesson): do not reorder reads/stages across phases without
// re-auditing the write-after-read rule.
#define NT2 32  // K_DIM / 64

__global__ __launch_bounds__(512, 2) void gemm8_kernel(
    const unsigned short* __restrict__ A,
    const unsigned short* __restrict__ Bw,
    unsigned short* __restrict__ C) {
  extern __shared__ __align__(16) char smem[];
  const int tid  = threadIdx.x;
  const int lane = tid & 63;
  const int wave = tid >> 6;
  const int wm = wave >> 2;   // 0..1  (M half)
  const int wn = wave & 3;    // 0..3  (N quarter)

  // XCD-aware mapping: concurrent set per XCD = 4 M-tiles x 8 N-tiles.
  // bid&7 -> XCD; M-tile = xcd*4 + (bid>>3)&3; N-tile = bid>>5. Bijective on 768.
  const int bid = blockIdx.x;
  const int tileM = ((bid & 7) * 4 + ((bid >> 3) & 3)) * 256;
  const int tileN = (bid >> 5) * 256;

  // staging: dest byte p = wave*2048 + L*1024 + lane*16 (linear);
  // logical q = p ^ ((p>>9)&1)<<5 -> (panel=q>>13, row=(q>>6)&127, off=q&63)
  const int p0i = wave * 2048 + lane * 16;
  const int p1i = p0i + 1024;
  const int q0i = p0i ^ (((p0i >> 9) & 1) << 5);
  const int q1i = p1i ^ (((p1i >> 9) & 1) << 5);
  const int go0 = ((q0i >> 6) & 127) * 4096 + ((q0i >> 13) << 6) + (q0i & 63);
  const int go1 = ((q1i >> 6) & 127) * 4096 + ((q1i >> 13) << 6) + (q1i & 63);
  const char* Ab = (const char*)A + (size_t)tileM * 4096;
  const char* Bb = (const char*)Bw + (size_t)tileN * 4096;

#define STAGE(kt, h, bufOff)                                                 \
  {                                                                          \
    const char* gs_ = ((h) < 2 ? Ab : Bb) +                                  \
                      (size_t)(((h) & 1) * 128) * 4096 + (size_t)(kt) * 128; \
    char* ds_ = smem + (bufOff) + (h) * 16384 + wave * 2048;                 \
    __builtin_amdgcn_global_load_lds(                                        \
        (const __attribute__((address_space(1))) void*)(gs_ + go0),          \
        (__attribute__((address_space(3))) void*)ds_, 16, 0, 0);             \
    __builtin_amdgcn_global_load_lds(                                        \
        (const __attribute__((address_space(1))) void*)(gs_ + go1),          \
        (__attribute__((address_space(3))) void*)(ds_ + 1024), 16, 0, 0);    \
  }

  // ds_read fragment bases (swizzled)
  const int xbit = ((lane >> 3) & 1) << 5;  // row bit3 -> flip byte bit5
  const int aBase = wm * 16384 +
                    (((lane & 15) * 64 + (lane >> 4) * 16) ^ xbit);
  const int bBase = 32768 + (wn >> 1) * 16384 +
                    ((((wn & 1) * 64 + (lane & 15)) * 64 + (lane >> 4) * 16) ^ xbit);

#define RDA(m, bufOff)                                                          \
  a[m][0] = *reinterpret_cast<const bf16x8*>(smem + (bufOff) + aBase + (m) * 1024);        \
  a[m][1] = *reinterpret_cast<const bf16x8*>(smem + (bufOff) + aBase + (m) * 1024 + 8192);
#define RDB(n, bufOff)                                                          \
  b[n][0] = *reinterpret_cast<const bf16x8*>(smem + (bufOff) + bBase + (n) * 1024);        \
  b[n][1] = *reinterpret_cast<const bf16x8*>(smem + (bufOff) + bBase + (n) * 1024 + 8192);
#define MM(m, n)                                                                \
  acc[m][n] = __builtin_amdgcn_mfma_f32_16x16x32_bf16(a[m][0], b[n][0], acc[m][n], 0, 0, 0); \
  acc[m][n] = __builtin_amdgcn_mfma_f32_16x16x32_bf16(a[m][1], b[n][1], acc[m][n], 0, 0, 0);

  bf16x8 a[8][2], b[4][2];
  f32x4 acc[8][4] = {};

  // prologue (steady-state priming): tile0 fully + tile1 fully; vmcnt(8)
  // drains tile0, leaving (1,h0..h3)=8 in flight — exactly the loop-top
  // state. Then pre-issue phase-0's fragment reads (a[0-3], b[0-1], tile0).
  STAGE(0, 0, 0); STAGE(0, 1, 0); STAGE(0, 2, 0); STAGE(0, 3, 0);
  STAGE(1, 0, 65536); STAGE(1, 1, 65536); STAGE(1, 2, 65536); STAGE(1, 3, 65536);
  asm volatile("s_waitcnt vmcnt(8)" ::: "memory");
  __builtin_amdgcn_s_barrier();
  RDA(0, 0); RDA(1, 0); RDA(2, 0); RDA(3, 0);
  RDB(0, 0); RDB(1, 0);

  for (int j = 0; j < NT2; ++j) {
    const int buf  = (j & 1) << 16;
    const int nbuf = buf ^ 65536;
    // ---- phase 0: MFMA(0-3 x 0-1); prefetch a[4-7] ----
    __builtin_amdgcn_s_setprio(1);
    RDA(4, buf); RDA(5, buf); RDA(6, buf); RDA(7, buf);
    MM(0, 0); MM(0, 1); MM(1, 0); MM(1, 1);
    MM(2, 0); MM(2, 1); MM(3, 0); MM(3, 1);
    __builtin_amdgcn_s_setprio(0);
    __builtin_amdgcn_s_barrier();
    // ---- phase 1: MFMA(4-7 x 0-1); prefetch b[2-3] ----
    __builtin_amdgcn_s_setprio(1);
    RDB(2, buf); RDB(3, buf);
    MM(4, 0); MM(4, 1); MM(5, 0); MM(5, 1);
    MM(6, 0); MM(6, 1); MM(7, 0); MM(7, 1);
    __builtin_amdgcn_s_setprio(0);
    __builtin_amdgcn_s_barrier();
    // ---- phase 2: MFMA(0-3 x 2-3); stage (j+2,h0)->buf ----
    __builtin_amdgcn_s_setprio(1);
    if (j < NT2 - 2) STAGE(j + 2, 0, buf);
    MM(0, 2); MM(0, 3); MM(1, 2); MM(1, 3);
    MM(2, 2); MM(2, 3); MM(3, 2); MM(3, 3);
    __builtin_amdgcn_s_setprio(0);
    __builtin_amdgcn_s_barrier();
    // ---- phase 3: stage (j+2,h1..h3)->buf; vmcnt(8) completes tile j+1,
    //      leaves all of tile j+2 in flight; barrier; hoist next phase-0
    //      reads (a[0-3],b[0-1] from nbuf); MFMA(4-7 x 2-3) ----
    if (j < NT2 - 2) {
      STAGE(j + 2, 1, buf);
      STAGE(j + 2, 2, buf);
      STAGE(j + 2, 3, buf);
      asm volatile("s_waitcnt vmcnt(8)" ::: "memory");
    } else if (j == NT2 - 2) {
      asm volatile("s_waitcnt vmcnt(0)" ::: "memory");
    }
    __builtin_amdgcn_s_barrier();
    __builtin_amdgcn_s_setprio(1);
    RDA(0, nbuf); RDA(1, nbuf); RDA(2, nbuf); RDA(3, nbuf);
    RDB(0, nbuf); RDB(1, nbuf);
    MM(4, 2); MM(4, 3); MM(5, 2); MM(5, 3);
    MM(6, 2); MM(6, 3); MM(7, 2); MM(7, 3);
    __builtin_amdgcn_s_setprio(0);
    __builtin_amdgcn_s_barrier();
  }

  // epilogue: C/D layout col=lane&15, row=(lane>>4)*4+jj
  const int crow = (lane >> 4) * 4;
  const int ccol = lane & 15;
#pragma unroll
  for (int m = 0; m < 8; ++m) {
#pragma unroll
    for (int n = 0; n < 4; ++n) {
#pragma unroll
      for (int jj = 0; jj < 4; ++jj) {
        int row = tileM + wm * 128 + m * 16 + crow + jj;
        int col = tileN + wn * 64 + n * 16 + ccol;
        C[(size_t)row * E_DIM + col] = f2bf(acc[m][n][jj]);
      }
    }
  }
#undef STAGE
#undef RDA
#undef RDB
#undef MM
}

// ---------------- blocked parallel scan ----------------
// P1: per (b,d,chunk) affine composition over CH2 steps.
// R8: 8 d's per thread, bf16x8 16B loads (coalescing sweet spot).
__global__ __launch_bounds__(256) void scan_p1_kernel(
    const unsigned short* __restrict__ ufr,
    unsigned short* __restrict__ Aout, unsigned short* __restrict__ Bout) {
  const int idx8 = blockIdx.x * 256 + threadIdx.x;  // (b, d/8): 2048 total
  const int s = blockIdx.y;
  const int b = idx8 >> 8;            // 256 d-groups per b
  const int d = (idx8 & 255) * 8;
  const unsigned short* up =
      ufr + ((size_t)(s * CH2) * B_DIM + b) * E_DIM + d;
  float Av[8], Bv[8];
#pragma unroll
  for (int q = 0; q < 8; ++q) { Av[q] = 1.f; Bv[q] = 0.f; }
#pragma unroll
  for (int it = 0; it < CH2; ++it) {
    u16x8 uv = *reinterpret_cast<const u16x8*>(up);
    u16x8 fv = *reinterpret_cast<const u16x8*>(up + D_DIM);
#pragma unroll
    for (int q = 0; q < 8; ++q) {
      float f = fast_sigmoid(bf2f(fv[q]));
      Av[q] *= f;
      Bv[q] = f * Bv[q] + (1.f - f) * bf2f(uv[q]);
    }
    up += (size_t)B_DIM * E_DIM;
  }
  size_t o = (size_t)s * BD + b * D_DIM + d;
  u16x8 ao, bo;
#pragma unroll
  for (int q = 0; q < 8; ++q) { ao[q] = f2bf(Av[q]); bo[q] = f2bf(Bv[q]); }
  *reinterpret_cast<u16x8*>(Aout + o) = ao;
  *reinterpret_cast<u16x8*>(Bout + o) = bo;
}

// P2: compose chunk boundaries sequentially.
// R8: batch-8 double-buffered prefetch hides the L2/L3 load latency of the
// serial 128-step chain. Named arrays + full unroll keep registers (rule #20).
__global__ __launch_bounds__(64) void scan_p2_kernel(
    const float* __restrict__ c0,
    const unsigned short* __restrict__ Ain, const unsigned short* __restrict__ Bin,
    unsigned short* __restrict__ cs, float* __restrict__ cT) {
  const int idx = blockIdx.x * 64 + threadIdx.x;
  float c = c0[idx];
  unsigned short aP[8], bP[8], aQ[8], bQ[8];
#define LOADB(AA, BB, sb)                                          \
  _Pragma("unroll")                                                \
  for (int q = 0; q < 8; ++q) {                                    \
    AA[q] = Ain[(size_t)((sb) + q) * BD + idx];                    \
    BB[q] = Bin[(size_t)((sb) + q) * BD + idx];                    \
  }
#define COMPB(AA, BB, sb)                                          \
  _Pragma("unroll")                                                \
  for (int q = 0; q < 8; ++q) {                                    \
    cs[(size_t)((sb) + q) * BD + idx] = f2bf(c);                   \
    c = bf2f(AA[q]) * c + bf2f(BB[q]);                             \
  }
  LOADB(aP, bP, 0);
  for (int sb = 0; sb < S2; sb += 16) {
    LOADB(aQ, bQ, sb + 8);
    COMPB(aP, bP, sb);
    if (sb + 16 < S2) { LOADB(aP, bP, sb + 16); }
    COMPB(aQ, bQ, sb + 8);
  }
#undef LOADB
#undef COMPB
  cT[idx] = c;
}

// P3 fused with GELU+LN: block = (b, chunk); 256 threads cover all D=2048.
// Re-runs CH2 steps from the chunk start state, then per-t block-LN, writes out.
// R6: x as bf16. R7: cs as bf16. R8: 16B loads. R9: tanh-form GELU.
// R10: red[] double-buffered by t-parity — one __syncthreads per t-step.
__global__ __launch_bounds__(256) void scan_p3ln_kernel(
    const unsigned short* __restrict__ xb,
    const unsigned short* __restrict__ ufr,
    const unsigned short* __restrict__ csb,
    const float* __restrict__ gamma,
    const float* __restrict__ beta,
    float* __restrict__ out) {
  const int b = blockIdx.x & (B_DIM - 1);
  const int s = blockIdx.x >> 3;
  const int tid = threadIdx.x;
  const int lane = tid & 63;
  const int wave = tid >> 6;
  const int d0 = tid * 8;
  __shared__ float red[16];

  float c[8];
  {
    u16x8 v = *reinterpret_cast<const u16x8*>(csb + (size_t)s * BD + b * D_DIM + d0);
#pragma unroll
    for (int q = 0; q < 8; ++q) c[q] = bf2f(v[q]);
  }
  float gam[8], bet[8];
  {
    float4 g0 = *(const float4*)(gamma + d0);
    float4 g1 = *(const float4*)(gamma + d0 + 4);
    float4 b0 = *(const float4*)(beta + d0);
    float4 b1 = *(const float4*)(beta + d0 + 4);
    gam[0]=g0.x; gam[1]=g0.y; gam[2]=g0.z; gam[3]=g0.w;
    gam[4]=g1.x; gam[5]=g1.y; gam[6]=g1.z; gam[7]=g1.w;
    bet[0]=b0.x; bet[1]=b0.y; bet[2]=b0.z; bet[3]=b0.w;
    bet[4]=b1.x; bet[5]=b1.y; bet[6]=b1.z; bet[7]=b1.w;
  }

  for (int it = 0; it < CH2; ++it) {
    const size_t rowo = (size_t)(s * CH2 + it) * B_DIM + b;
    const unsigned short* up = ufr + rowo * E_DIM + d0;
    u16x8 uv = *reinterpret_cast<const u16x8*>(up);
    u16x8 fv = *reinterpret_cast<const u16x8*>(up + D_DIM);
    u16x8 rv = *reinterpret_cast<const u16x8*>(up + 2 * D_DIM);
    u16x8 xv = *reinterpret_cast<const u16x8*>(xb + rowo * D_DIM + d0);

    float g[8];
    float s1 = 0.f, sq = 0.f;
#pragma unroll
    for (int jj = 0; jj < 8; ++jj) {
      float f = fast_sigmoid(bf2f(fv[jj]));
      float r = fast_sigmoid(bf2f(rv[jj]));
      c[jj] = f * c[jj] + (1.f - f) * bf2f(uv[jj]);
      float h = r * fast_tanh(c[jj]) + (1.f - r) * bf2f(xv[jj]);
      float t = fast_tanh(0.79788456f * (h + 0.044715f * h * h * h));
      float gg = 0.5f * h * (1.f + t);
      g[jj] = gg;
      s1 += gg;
      sq += gg * gg;
    }
#pragma unroll
    for (int off = 32; off; off >>= 1) {
      s1 += __shfl_xor(s1, off);
      sq += __shfl_xor(sq, off);
    }
    float* rb = red + (it & 1) * 8;
    if (lane == 0) { rb[wave] = s1; rb[4 + wave] = sq; }
    __syncthreads();
    float S1 = rb[0] + rb[1] + rb[2] + rb[3];
    float Sq = rb[4] + rb[5] + rb[6] + rb[7];
    float mean = S1 * (1.f / D_DIM);
    float var  = Sq * (1.f / D_DIM) - mean * mean;
    float inv = rsqrtf(var + LN_EPS);

    float* op = out + rowo * D_DIM + d0;
    float4 o0 = {(g[0] - mean) * inv * gam[0] + bet[0],
                 (g[1] - mean) * inv * gam[1] + bet[1],
                 (g[2] - mean) * inv * gam[2] + bet[2],
                 (g[3] - mean) * inv * gam[3] + bet[3]};
    float4 o1 = {(g[4] - mean) * inv * gam[4] + bet[4],
                 (g[5] - mean) * inv * gam[5] + bet[5],
                 (g[6] - mean) * inv * gam[6] + bet[6],
                 (g[7] - mean) * inv * gam[7] + bet[7]};
    *(float4*)op = o0;
    *(float4*)(op + 4) = o1;
  }
}

extern "C" void kernel_launch(void* const* d_in, const int* in_sizes, int n_in,
                              void* d_out, int out_size, void* d_ws, size_t ws_size,
                              hipStream_t stream) {
  const float* x     = (const float*)d_in[0];
  const float* c0    = (const float*)d_in[1];
  const float* W     = (const float*)d_in[2];
  const float* gamma = (const float*)d_in[3];
  const float* beta  = (const float*)d_in[4];
  float* out = (float*)d_out;
  float* cT  = out + (size_t)N_ROWS * D_DIM;

  unsigned short* ufr = (unsigned short*)d_ws;                 // [N_ROWS][E] bf16
  unsigned short* xb  = ufr + (size_t)N_ROWS * E_DIM;          // [N_ROWS][K] bf16
  unsigned short* wb  = xb + (size_t)N_ROWS * K_DIM;           // [E][K] bf16

  // scan scratch reuses wb region (dead after gemm; xb stays live for p3):
  // 3 * S2*BD*2 = 12.6MB < 25.2MB (wb size). All bf16.
  unsigned short* Abuf = wb;
  unsigned short* Bbuf = Abuf + (size_t)S2 * BD;
  unsigned short* csb  = Bbuf + (size_t)S2 * BD;

  int nx8 = N_ROWS * K_DIM / 8;
  int nw8 = E_DIM * K_DIM / 8;
  cvt2_kernel<<<(nx8 + nw8 + 255) / 256, 256, 0, stream>>>(x, xb, nx8, W, wb, nw8);

  (void)hipFuncSetAttribute((const void*)gemm8_kernel,
                            hipFuncAttributeMaxDynamicSharedMemorySize, 131072);
  gemm8_kernel<<<768, 512, 131072, stream>>>(xb, wb, ufr);

  dim3 sg(BD / 8 / 256, S2);  // (8, 128)
  scan_p1_kernel<<<sg, 256, 0, stream>>>(ufr, Abuf, Bbuf);
  scan_p2_kernel<<<BD / 64, 64, 0, stream>>>(c0, Abuf, Bbuf, csb, cT);
  scan_p3ln_kernel<<<B_DIM * S2, 256, 0, stream>>>(xb, ufr, csb, gamma, beta, out);
}

// Round 12
// 256.575 us; speedup vs baseline: 1.0604x; 1.0604x over previous
//
#include <hip/hip_runtime.h>
#include <hip/hip_bf16.h>

#define T_DIM 1024
#define B_DIM 8
#define D_DIM 2048
#define E_DIM 6144   // 3*D
#define N_ROWS 8192  // T*B
#define K_DIM 2048
#define LN_EPS 1e-5f

#define S2  128   // scan chunks
#define CH2 8     // T per chunk
#define BD (B_DIM * D_DIM)  // 16384

typedef short bf16x8 __attribute__((ext_vector_type(8)));
typedef unsigned short u16x8 __attribute__((ext_vector_type(8)));
typedef float f32x4 __attribute__((ext_vector_type(4)));

__device__ __forceinline__ unsigned short f2bf(float f) {
  unsigned u = __float_as_uint(f);
  u += 0x7fffu + ((u >> 16) & 1u);  // round-to-nearest-even
  return (unsigned short)(u >> 16);
}
__device__ __forceinline__ float bf2f(unsigned short h) {
  return __uint_as_float(((unsigned)h) << 16);
}
__device__ __forceinline__ float fast_sigmoid(float x) {
  return __builtin_amdgcn_rcpf(1.f + __expf(-x));
}
__device__ __forceinline__ float fast_tanh(float x) {
  return 1.f - 2.f * __builtin_amdgcn_rcpf(__expf(2.f * x) + 1.f);
}

// ------- f32 -> bf16 conversion (8 elems/thread, 16B stores) -------
__global__ __launch_bounds__(256) void cvt2_kernel(
    const float* __restrict__ src0, unsigned short* __restrict__ dst0, int n0,
    const float* __restrict__ src1, unsigned short* __restrict__ dst1, int n1) {
  int i = blockIdx.x * 256 + threadIdx.x;  // group of 8 floats
  const float* s;
  unsigned short* d;
  if (i < n0) {
    s = src0; d = dst0;
  } else {
    i -= n0;
    if (i >= n1) return;
    s = src1; d = dst1;
  }
  float4 v0 = reinterpret_cast<const float4*>(s)[i * 2];
  float4 v1 = reinterpret_cast<const float4*>(s)[i * 2 + 1];
  u16x8 o;
  o[0] = f2bf(v0.x); o[1] = f2bf(v0.y); o[2] = f2bf(v0.z); o[3] = f2bf(v0.w);
  o[4] = f2bf(v1.x); o[5] = f2bf(v1.y); o[6] = f2bf(v1.z); o[7] = f2bf(v1.w);
  *reinterpret_cast<u16x8*>(d + (size_t)i * 8) = o;
}

// ============ 256x256 8-phase bf16 MFMA GEMM (T1+T2+T3/T4+T5) ============
// C[N_ROWS,E] = A[N_ROWS,K] * Bw[E,K]^T, all bf16, f32 accumulate.
// 512 threads = 8 waves (2M x 4N). BK=64. LDS = 2 buffers x (A 32KB + B 32KB).
// Half-tile layout: 2 k-panels (ks=0/1) of [128 rows][32 bf16] (64B rows),
// swizzled byte^=((b>>9)&1)<<5; staged linear-dest with inverse-swz source.
//
// R12 = R9's GEMM verbatim (verified 175.4us, MfmaUtil 53, 0 conflicts):
// R2 ds_read pipeline (reads one phase ahead, inside previous MFMA region);
// one STAGE per phase (distributed memory issue — R10/R11's clustered
// 3-STAGE ph3 regressed 17% with BOTH vmcnt(6) and vmcnt(8): the uniform
// interleave, not prefetch depth, is what matters); no phase-top lgkmcnt
// (compiler emits fine-grained per-use waits); ph3 vmcnt(4)+barrier drains
// the entire next tile before the hoisted cross-buffer reads.
// NOTE (R4 lesson): do not reorder reads/stages across phases without
// re-auditing the write-after-read rule.
#define NT2 32  // K_DIM / 64

__global__ __launch_bounds__(512, 2) void gemm8_kernel(
    const unsigned short* __restrict__ A,
    const unsigned short* __restrict__ Bw,
    unsigned short* __restrict__ C) {
  extern __shared__ __align__(16) char smem[];
  const int tid  = threadIdx.x;
  const int lane = tid & 63;
  const int wave = tid >> 6;
  const int wm = wave >> 2;   // 0..1  (M half)
  const int wn = wave & 3;    // 0..3  (N quarter)

  // XCD-aware mapping: concurrent set per XCD = 4 M-tiles x 8 N-tiles.
  // bid&7 -> XCD; M-tile = xcd*4 + (bid>>3)&3; N-tile = bid>>5. Bijective on 768.
  const int bid = blockIdx.x;
  const int tileM = ((bid & 7) * 4 + ((bid >> 3) & 3)) * 256;
  const int tileN = (bid >> 5) * 256;

  // staging: dest byte p = wave*2048 + L*1024 + lane*16 (linear);
  // logical q = p ^ ((p>>9)&1)<<5 -> (panel=q>>13, row=(q>>6)&127, off=q&63)
  const int p0i = wave * 2048 + lane * 16;
  const int p1i = p0i + 1024;
  const int q0i = p0i ^ (((p0i >> 9) & 1) << 5);
  const int q1i = p1i ^ (((p1i >> 9) & 1) << 5);
  const int go0 = ((q0i >> 6) & 127) * 4096 + ((q0i >> 13) << 6) + (q0i & 63);
  const int go1 = ((q1i >> 6) & 127) * 4096 + ((q1i >> 13) << 6) + (q1i & 63);
  const char* Ab = (const char*)A + (size_t)tileM * 4096;
  const char* Bb = (const char*)Bw + (size_t)tileN * 4096;

#define STAGE(kt, h, bufOff)                                                 \
  {                                                                          \
    const char* gs_ = ((h) < 2 ? Ab : Bb) +                                  \
                      (size_t)(((h) & 1) * 128) * 4096 + (size_t)(kt) * 128; \
    char* ds_ = smem + (bufOff) + (h) * 16384 + wave * 2048;                 \
    __builtin_amdgcn_global_load_lds(                                        \
        (const __attribute__((address_space(1))) void*)(gs_ + go0),          \
        (__attribute__((address_space(3))) void*)ds_, 16, 0, 0);             \
    __builtin_amdgcn_global_load_lds(                                        \
        (const __attribute__((address_space(1))) void*)(gs_ + go1),          \
        (__attribute__((address_space(3))) void*)(ds_ + 1024), 16, 0, 0);    \
  }

  // ds_read fragment bases (swizzled)
  const int xbit = ((lane >> 3) & 1) << 5;  // row bit3 -> flip byte bit5
  const int aBase = wm * 16384 +
                    (((lane & 15) * 64 + (lane >> 4) * 16) ^ xbit);
  const int bBase = 32768 + (wn >> 1) * 16384 +
                    ((((wn & 1) * 64 + (lane & 15)) * 64 + (lane >> 4) * 16) ^ xbit);

#define RDA(m, bufOff)                                                          \
  a[m][0] = *reinterpret_cast<const bf16x8*>(smem + (bufOff) + aBase + (m) * 1024);        \
  a[m][1] = *reinterpret_cast<const bf16x8*>(smem + (bufOff) + aBase + (m) * 1024 + 8192);
#define RDB(n, bufOff)                                                          \
  b[n][0] = *reinterpret_cast<const bf16x8*>(smem + (bufOff) + bBase + (n) * 1024);        \
  b[n][1] = *reinterpret_cast<const bf16x8*>(smem + (bufOff) + bBase + (n) * 1024 + 8192);
#define MM(m, n)                                                                \
  acc[m][n] = __builtin_amdgcn_mfma_f32_16x16x32_bf16(a[m][0], b[n][0], acc[m][n], 0, 0, 0); \
  acc[m][n] = __builtin_amdgcn_mfma_f32_16x16x32_bf16(a[m][1], b[n][1], acc[m][n], 0, 0, 0);

  bf16x8 a[8][2], b[4][2];
  f32x4 acc[8][4] = {};

  // prologue: stage tile0 fully + tile1 h0,h1; drain tile0 (8 oldest of 12);
  // then pre-issue phase-0's fragment reads (a[0-3], b[0-1] of tile 0).
  STAGE(0, 0, 0); STAGE(0, 1, 0); STAGE(0, 2, 0); STAGE(0, 3, 0);
  STAGE(1, 0, 65536); STAGE(1, 1, 65536);
  asm volatile("s_waitcnt vmcnt(4)" ::: "memory");
  __builtin_amdgcn_s_barrier();
  RDA(0, 0); RDA(1, 0); RDA(2, 0); RDA(3, 0);
  RDB(0, 0); RDB(1, 0);

  for (int j = 0; j < NT2; ++j) {
    const int buf  = (j & 1) << 16;
    const int nbuf = buf ^ 65536;
    // ---- phase 0: MFMA(0-3 x 0-1); prefetch a[4-7]; stage (j+1,h2) ----
    __builtin_amdgcn_s_setprio(1);
    if (j < NT2 - 1) STAGE(j + 1, 2, nbuf);
    RDA(4, buf); RDA(5, buf); RDA(6, buf); RDA(7, buf);
    MM(0, 0); MM(0, 1); MM(1, 0); MM(1, 1);
    MM(2, 0); MM(2, 1); MM(3, 0); MM(3, 1);
    __builtin_amdgcn_s_setprio(0);
    __builtin_amdgcn_s_barrier();
    // ---- phase 1: MFMA(4-7 x 0-1); prefetch b[2-3]; stage (j+1,h3) ----
    __builtin_amdgcn_s_setprio(1);
    if (j < NT2 - 1) STAGE(j + 1, 3, nbuf);
    RDB(2, buf); RDB(3, buf);
    MM(4, 0); MM(4, 1); MM(5, 0); MM(5, 1);
    MM(6, 0); MM(6, 1); MM(7, 0); MM(7, 1);
    __builtin_amdgcn_s_setprio(0);
    __builtin_amdgcn_s_barrier();
    // ---- phase 2: MFMA(0-3 x 2-3); stage (j+2,h0)->buf ----
    // (buf A-reads all completed by ph1 consumption + ph1 barrier)
    __builtin_amdgcn_s_setprio(1);
    if (j < NT2 - 2) STAGE(j + 2, 0, buf);
    MM(0, 2); MM(0, 3); MM(1, 2); MM(1, 3);
    MM(2, 2); MM(2, 3); MM(3, 2); MM(3, 3);
    __builtin_amdgcn_s_setprio(0);
    __builtin_amdgcn_s_barrier();
    // ---- phase 3: stage (j+2,h1)->buf; drain tile j+1; MFMA(4-7 x 2-3);
    //      hoist next iteration's phase-0 reads (a[0-3],b[0-1] from nbuf) ----
    if (j < NT2 - 2) {
      STAGE(j + 2, 1, buf);
      asm volatile("s_waitcnt vmcnt(4)" ::: "memory");   // completes tile j+1
    } else if (j == NT2 - 2) {
      asm volatile("s_waitcnt vmcnt(0)" ::: "memory");
    }
    __builtin_amdgcn_s_barrier();
    __builtin_amdgcn_s_setprio(1);
    RDA(0, nbuf); RDA(1, nbuf); RDA(2, nbuf); RDA(3, nbuf);
    RDB(0, nbuf); RDB(1, nbuf);
    MM(4, 2); MM(4, 3); MM(5, 2); MM(5, 3);
    MM(6, 2); MM(6, 3); MM(7, 2); MM(7, 3);
    __builtin_amdgcn_s_setprio(0);
    __builtin_amdgcn_s_barrier();
  }

  // epilogue: C/D layout col=lane&15, row=(lane>>4)*4+jj
  const int crow = (lane >> 4) * 4;
  const int ccol = lane & 15;
#pragma unroll
  for (int m = 0; m < 8; ++m) {
#pragma unroll
    for (int n = 0; n < 4; ++n) {
#pragma unroll
      for (int jj = 0; jj < 4; ++jj) {
        int row = tileM + wm * 128 + m * 16 + crow + jj;
        int col = tileN + wn * 64 + n * 16 + ccol;
        C[(size_t)row * E_DIM + col] = f2bf(acc[m][n][jj]);
      }
    }
  }
#undef STAGE
#undef RDA
#undef RDB
#undef MM
}

// ---------------- blocked parallel scan ----------------
// P1: per (b,d,chunk) affine composition over CH2 steps.
// R8: 8 d's per thread, bf16x8 16B loads (coalescing sweet spot).
__global__ __launch_bounds__(256) void scan_p1_kernel(
    const unsigned short* __restrict__ ufr,
    unsigned short* __restrict__ Aout, unsigned short* __restrict__ Bout) {
  const int idx8 = blockIdx.x * 256 + threadIdx.x;  // (b, d/8): 2048 total
  const int s = blockIdx.y;
  const int b = idx8 >> 8;            // 256 d-groups per b
  const int d = (idx8 & 255) * 8;
  const unsigned short* up =
      ufr + ((size_t)(s * CH2) * B_DIM + b) * E_DIM + d;
  float Av[8], Bv[8];
#pragma unroll
  for (int q = 0; q < 8; ++q) { Av[q] = 1.f; Bv[q] = 0.f; }
#pragma unroll
  for (int it = 0; it < CH2; ++it) {
    u16x8 uv = *reinterpret_cast<const u16x8*>(up);
    u16x8 fv = *reinterpret_cast<const u16x8*>(up + D_DIM);
#pragma unroll
    for (int q = 0; q < 8; ++q) {
      float f = fast_sigmoid(bf2f(fv[q]));
      Av[q] *= f;
      Bv[q] = f * Bv[q] + (1.f - f) * bf2f(uv[q]);
    }
    up += (size_t)B_DIM * E_DIM;
  }
  size_t o = (size_t)s * BD + b * D_DIM + d;
  u16x8 ao, bo;
#pragma unroll
  for (int q = 0; q < 8; ++q) { ao[q] = f2bf(Av[q]); bo[q] = f2bf(Bv[q]); }
  *reinterpret_cast<u16x8*>(Aout + o) = ao;
  *reinterpret_cast<u16x8*>(Bout + o) = bo;
}

// P2: compose chunk boundaries sequentially.
// R8: batch-8 double-buffered prefetch hides the L2/L3 load latency of the
// serial 128-step chain. Named arrays + full unroll keep registers (rule #20).
__global__ __launch_bounds__(64) void scan_p2_kernel(
    const float* __restrict__ c0,
    const unsigned short* __restrict__ Ain, const unsigned short* __restrict__ Bin,
    unsigned short* __restrict__ cs, float* __restrict__ cT) {
  const int idx = blockIdx.x * 64 + threadIdx.x;
  float c = c0[idx];
  unsigned short aP[8], bP[8], aQ[8], bQ[8];
#define LOADB(AA, BB, sb)                                          \
  _Pragma("unroll")                                                \
  for (int q = 0; q < 8; ++q) {                                    \
    AA[q] = Ain[(size_t)((sb) + q) * BD + idx];                    \
    BB[q] = Bin[(size_t)((sb) + q) * BD + idx];                    \
  }
#define COMPB(AA, BB, sb)                                          \
  _Pragma("unroll")                                                \
  for (int q = 0; q < 8; ++q) {                                    \
    cs[(size_t)((sb) + q) * BD + idx] = f2bf(c);                   \
    c = bf2f(AA[q]) * c + bf2f(BB[q]);                             \
  }
  LOADB(aP, bP, 0);
  for (int sb = 0; sb < S2; sb += 16) {
    LOADB(aQ, bQ, sb + 8);
    COMPB(aP, bP, sb);
    if (sb + 16 < S2) { LOADB(aP, bP, sb + 16); }
    COMPB(aQ, bQ, sb + 8);
  }
#undef LOADB
#undef COMPB
  cT[idx] = c;
}

// P3 fused with GELU+LN: block = (b, chunk); 256 threads cover all D=2048.
// Re-runs CH2 steps from the chunk start state, then per-t block-LN, writes out.
// R6: x as bf16. R7: cs as bf16. R8: 16B loads. R9: tanh-form GELU.
// R10/R11: red[] double-buffered by t-parity — ONE __syncthreads per t-step;
// the removed trailing barrier lets the next t-step's global loads hoist
// above the LN write-back (the scan-side win R10/R11's gemm regression hid).
__global__ __launch_bounds__(256) void scan_p3ln_kernel(
    const unsigned short* __restrict__ xb,
    const unsigned short* __restrict__ ufr,
    const unsigned short* __restrict__ csb,
    const float* __restrict__ gamma,
    const float* __restrict__ beta,
    float* __restrict__ out) {
  const int b = blockIdx.x & (B_DIM - 1);
  const int s = blockIdx.x >> 3;
  const int tid = threadIdx.x;
  const int lane = tid & 63;
  const int wave = tid >> 6;
  const int d0 = tid * 8;
  __shared__ float red[16];

  float c[8];
  {
    u16x8 v = *reinterpret_cast<const u16x8*>(csb + (size_t)s * BD + b * D_DIM + d0);
#pragma unroll
    for (int q = 0; q < 8; ++q) c[q] = bf2f(v[q]);
  }
  float gam[8], bet[8];
  {
    float4 g0 = *(const float4*)(gamma + d0);
    float4 g1 = *(const float4*)(gamma + d0 + 4);
    float4 b0 = *(const float4*)(beta + d0);
    float4 b1 = *(const float4*)(beta + d0 + 4);
    gam[0]=g0.x; gam[1]=g0.y; gam[2]=g0.z; gam[3]=g0.w;
    gam[4]=g1.x; gam[5]=g1.y; gam[6]=g1.z; gam[7]=g1.w;
    bet[0]=b0.x; bet[1]=b0.y; bet[2]=b0.z; bet[3]=b0.w;
    bet[4]=b1.x; bet[5]=b1.y; bet[6]=b1.z; bet[7]=b1.w;
  }

  for (int it = 0; it < CH2; ++it) {
    const size_t rowo = (size_t)(s * CH2 + it) * B_DIM + b;
    const unsigned short* up = ufr + rowo * E_DIM + d0;
    u16x8 uv = *reinterpret_cast<const u16x8*>(up);
    u16x8 fv = *reinterpret_cast<const u16x8*>(up + D_DIM);
    u16x8 rv = *reinterpret_cast<const u16x8*>(up + 2 * D_DIM);
    u16x8 xv = *reinterpret_cast<const u16x8*>(xb + rowo * D_DIM + d0);

    float g[8];
    float s1 = 0.f, sq = 0.f;
#pragma unroll
    for (int jj = 0; jj < 8; ++jj) {
      float f = fast_sigmoid(bf2f(fv[jj]));
      float r = fast_sigmoid(bf2f(rv[jj]));
      c[jj] = f * c[jj] + (1.f - f) * bf2f(uv[jj]);
      float h = r * fast_tanh(c[jj]) + (1.f - r) * bf2f(xv[jj]);
      float t = fast_tanh(0.79788456f * (h + 0.044715f * h * h * h));
      float gg = 0.5f * h * (1.f + t);
      g[jj] = gg;
      s1 += gg;
      sq += gg * gg;
    }
#pragma unroll
    for (int off = 32; off; off >>= 1) {
      s1 += __shfl_xor(s1, off);
      sq += __shfl_xor(sq, off);
    }
    float* rb = red + (it & 1) * 8;
    if (lane == 0) { rb[wave] = s1; rb[4 + wave] = sq; }
    __syncthreads();
    float S1 = rb[0] + rb[1] + rb[2] + rb[3];
    float Sq = rb[4] + rb[5] + rb[6] + rb[7];
    float mean = S1 * (1.f / D_DIM);
    float var  = Sq * (1.f / D_DIM) - mean * mean;
    float inv = rsqrtf(var + LN_EPS);

    float* op = out + rowo * D_DIM + d0;
    float4 o0 = {(g[0] - mean) * inv * gam[0] + bet[0],
                 (g[1] - mean) * inv * gam[1] + bet[1],
                 (g[2] - mean) * inv * gam[2] + bet[2],
                 (g[3] - mean) * inv * gam[3] + bet[3]};
    float4 o1 = {(g[4] - mean) * inv * gam[4] + bet[4],
                 (g[5] - mean) * inv * gam[5] + bet[5],
                 (g[6] - mean) * inv * gam[6] + bet[6],
                 (g[7] - mean) * inv * gam[7] + bet[7]};
    *(float4*)op = o0;
    *(float4*)(op + 4) = o1;
  }
}

extern "C" void kernel_launch(void* const* d_in, const int* in_sizes, int n_in,
                              void* d_out, int out_size, void* d_ws, size_t ws_size,
                              hipStream_t stream) {
  const float* x     = (const float*)d_in[0];
  const float* c0    = (const float*)d_in[1];
  const float* W     = (const float*)d_in[2];
  const float* gamma = (const float*)d_in[3];
  const float* beta  = (const float*)d_in[4];
  float* out = (float*)d_out;
  float* cT  = out + (size_t)N_ROWS * D_DIM;

  unsigned short* ufr = (unsigned short*)d_ws;                 // [N_ROWS][E] bf16
  unsigned short* xb  = ufr + (size_t)N_ROWS * E_DIM;          // [N_ROWS][K] bf16
  unsigned short* wb  = xb + (size_t)N_ROWS * K_DIM;           // [E][K] bf16

  // scan scratch reuses wb region (dead after gemm; xb stays live for p3):
  // 3 * S2*BD*2 = 12.6MB < 25.2MB (wb size). All bf16.
  unsigned short* Abuf = wb;
  unsigned short* Bbuf = Abuf + (size_t)S2 * BD;
  unsigned short* csb  = Bbuf + (size_t)S2 * BD;

  int nx8 = N_ROWS * K_DIM / 8;
  int nw8 = E_DIM * K_DIM / 8;
  cvt2_kernel<<<(nx8 + nw8 + 255) / 256, 256, 0, stream>>>(x, xb, nx8, W, wb, nw8);

  (void)hipFuncSetAttribute((const void*)gemm8_kernel,
                            hipFuncAttributeMaxDynamicSharedMemorySize, 131072);
  gemm8_kernel<<<768, 512, 131072, stream>>>(xb, wb, ufr);

  dim3 sg(BD / 8 / 256, S2);  // (8, 128)
  scan_p1_kernel<<<sg, 256, 0, stream>>>(ufr, Abuf, Bbuf);
  scan_p2_kernel<<<BD / 64, 64, 0, stream>>>(c0, Abuf, Bbuf, csb, cT);
  scan_p3ln_kernel<<<B_DIM * S2, 256, 0, stream>>>(xb, ufr, csb, gamma, beta, out);
}